// Round 12
// baseline (296.491 us; speedup 1.0000x reference)
//
#include <hip/hip_runtime.h>

// Frame-wise E^H D E exact NDFT via separable phasors as two complex GEMMs on
// fp16 matrix cores (fp32 accumulate).
// v13 = v12 (221.3us best) with ONE change: adj_gemm split 512 -> 2x256-thread
// blocks per CU (yt-split, M=32 rows each, grid (NT,32) t-fastest so sibling
// blocks land on the same XCD with ~identical L2 footprints: same g rows, same
// ExT lines, Ey within 64B). Barrier drains / build-load waits of one block
// overlap the other's MFMA phase. Per-wave per-chunk work identical to v10
// (16 MFMA, straight-line loads, B-side rotation); plain stores, no atomics.
// fwd_gemm / prep_all: v12 verbatim.

#define NT 16
#define NK 2048
#define NXY 128
#define NC 8

typedef _Float16 f16x8 __attribute__((ext_vector_type(8)));
typedef float f32x4 __attribute__((ext_vector_type(4)));

union F8 { f16x8 h; uint u[4]; };

#define MFMA16(a, b, c) __builtin_amdgcn_mfma_f32_16x16x32_f16((a), (b), (c), 0, 0, 0)

__device__ __forceinline__ uint pack2h(float a, float b) {
    union { _Float16 h[2]; uint u; } p;
    p.h[0] = (_Float16)a; p.h[1] = (_Float16)b;
    return p.u;
}
__device__ __forceinline__ float2 unpack2h(uint v) {
    union { uint u; _Float16 h[2]; } p;
    p.u = v;
    return make_float2((float)p.h[0], (float)p.h[1]);
}
__device__ __forceinline__ uint rot16(uint v) { return (v >> 16) | (v << 16); }

// ---------------------------------------------------------------------------
// prep_all: fused preps, branch on block range (block-uniform divergence).
//  [0, 16384):      phasA -> tiled ExC [t][kt16][xc8][kp128][xq16] + linear
//                   EyL [t][k][y]
//  [16384, 32768):  phasB -> ExT [t][x][k]
//  [32768, 40960):  src   -> srcB fragment order [t][c][ch8][mf8][r16][xl16]
// ---------------------------------------------------------------------------
__global__ __launch_bounds__(256) void prep_all(const float* __restrict__ ktraj,
                                                const float* __restrict__ xin,
                                                const float* __restrict__ csmap,
                                                uint* __restrict__ ExC,
                                                uint* __restrict__ ExT,
                                                uint* __restrict__ EyL,
                                                uint* __restrict__ srcB) {
    const int b = blockIdx.x;
    const int tid = threadIdx.x;
    if (b < 16384) {
        // ---- phasA ----
        const int t = b >> 10;
        const int k = (b & 1023) * 2 + (tid >> 7);
        const int x = tid & 127;
        const float kx = ktraj[(size_t)k * NT + t];
        const float ky = ktraj[(size_t)(NK + k) * NT + t];
        const float xm = (float)(x - 64);
        float s, c;
        __sincosf(-kx * xm, &s, &c);
        ExC[((size_t)(t * 16 + (k >> 7)) * 8 + (x >> 4)) * 2048 +
            (size_t)(k & 127) * 16 + (x & 15)] = pack2h(c, s);
        __sincosf(-ky * xm, &s, &c);
        EyL[((size_t)t * NK + k) * NXY + x] = pack2h(c, s);
    } else if (b < 32768) {
        // ---- phasB ----
        const int q = b - 16384;
        const int t = q >> 10, x = (q >> 3) & 127, kz = q & 7;
        const int k = kz * 256 + tid;
        const float kx = ktraj[(size_t)k * NT + t];
        float s, c;
        __sincosf(-kx * (float)(x - 64), &s, &c);
        ExT[((size_t)t * NXY + x) * NK + k] = pack2h(c, s);
    } else {
        // ---- src ----
        const int idx = (b - 32768) * 256 + tid;   // < 2^21
        const int t = idx & 15, r = (idx >> 4) & 15, xl = (idx >> 8) & 15,
                  mf = (idx >> 12) & 7, ch = (idx >> 15) & 7, c = idx >> 18;
        const int x = ch * 16 + xl, y = mf * 16 + r;
        const float ir = xin[(size_t)(x * NXY + y) * NT + t];
        const float ii = xin[(size_t)NXY * NXY * NT + (size_t)(x * NXY + y) * NT + t];
        const float sr = csmap[(size_t)c * 2 * NXY * NXY + x * NXY + y];
        const float si = csmap[(size_t)c * 2 * NXY * NXY + NXY * NXY + x * NXY + y];
        srcB[((size_t)(t * NC + c) << 14) + ch * 2048 + mf * 256 + r * 16 + xl] =
            pack2h(sr * ir - si * ii, sr * ii + si * ir);
    }
}

// ---------------------------------------------------------------------------
// fwd_gemm: block = (t, c, kt of 64 kpoints), 256 thr, 4 waves.  (v12 verbatim)
// Wave ws owns kp slice [kt*64 + ws*16, +16) and ALL 8 mf rows. 1 B-load per
// chunk per wave, in-wave epilogue, B-side complex rotation.
// ---------------------------------------------------------------------------
__global__ __launch_bounds__(256, 2) void fwd_gemm(const uint* __restrict__ ExC,
                                                   const uint* __restrict__ EyL,
                                                   const uint* __restrict__ srcB,
                                                   const float* __restrict__ dcomp,
                                                   float2* __restrict__ g) {
    const int t = blockIdx.x, c = blockIdx.y, kt = blockIdx.z;
    const int tid = threadIdx.x, lane = tid & 63, ws = tid >> 6;
    const int quad = lane >> 4, l15 = lane & 15;

    __shared__ __align__(16) _Float16 As[2][4096];

    f32x4 accr[8], acci[8];
#pragma unroll
    for (int mf = 0; mf < 8; ++mf) { accr[mf] = (f32x4)0.0f; acci[mf] = (f32x4)0.0f; }

    const uint* srcT = srcB + ((size_t)(t * NC + c) << 14);
    const uint* exB = ExC + (size_t)(t * 16 + (kt >> 1)) * 16384;
    const int kin0 = (kt & 1) * 64 + ws * 16;            // this wave's kp base (128-tile)

    // prologue: stage + B load for chunk 0
    F8 vA0 = *(const F8*)(srcT + tid * 8);
    F8 vA1 = *(const F8*)(srcT + tid * 8 + 4);
    F8 Bc = *(const F8*)(exB + (kin0 + l15) * 16 + quad * 4);

#pragma unroll 2
    for (int ch = 0; ch < 8; ++ch) {
        const int buf = ch & 1;
        *(F8*)&As[buf][tid * 16] = vA0;
        *(F8*)&As[buf][tid * 16 + 8] = vA1;
        __syncthreads();
        const int chn = ch < 7 ? ch + 1 : 7;
        vA0 = *(const F8*)(srcT + chn * 2048 + tid * 8);
        vA1 = *(const F8*)(srcT + chn * 2048 + tid * 8 + 4);
        F8 Bn = *(const F8*)(exB + chn * 2048 + (kin0 + l15) * 16 + quad * 4);
        __builtin_amdgcn_sched_barrier(0);
        // B-side rotation: Br = (bR,-bI) for real part, Bi = (bI,bR) for imag
        F8 Br, Bi;
#pragma unroll
        for (int d = 0; d < 4; ++d) {
            Br.u[d] = Bc.u[d] ^ 0x80000000u;
            Bi.u[d] = rot16(Bc.u[d]);
        }
#pragma unroll
        for (int mf = 0; mf < 8; ++mf) {
            F8 Ap = *(const F8*)&As[buf][mf * 512 + l15 * 32 + quad * 8];
            accr[mf] = MFMA16(Ap.h, Br.h, accr[mf]);
            acci[mf] = MFMA16(Ap.h, Bi.h, acci[mf]);
        }
        Bc = Bn;
    }

    // epilogue: in-wave y-reduction with EyL (all 8 mf), quad-reduce, store g
    const int kpoint = kt * 64 + ws * 16 + l15;
    const uint* eyRow = EyL + ((size_t)t * NK + kpoint) * NXY;
    float kdr = 0.f, kdi = 0.f;
#pragma unroll
    for (int mf = 0; mf < 8; ++mf) {
        F8 e4 = *(const F8*)(eyRow + mf * 16 + quad * 4);
#pragma unroll
        for (int rr = 0; rr < 4; ++rr) {
            float2 ey = unpack2h(e4.u[rr]);
            float cr = accr[mf][rr], ci = acci[mf][rr];
            kdr += ey.x * cr - ey.y * ci;
            kdi += ey.x * ci + ey.y * cr;
        }
    }
    kdr += __shfl_xor(kdr, 16); kdr += __shfl_xor(kdr, 32);
    kdi += __shfl_xor(kdi, 16); kdi += __shfl_xor(kdi, 32);
    if (lane < 16) {
        float w = dcomp[(size_t)kpoint * NT + t] * (1.0f / 16384.0f);
        g[((size_t)t * NK + kpoint) * NC + c] = make_float2(kdr * w, kdi * w);
    }
}

// ---------------------------------------------------------------------------
// adj_gemm: block = (t, ytile of 4 y), 256 thr (4 waves), 2 blocks/CU.
// GEMM C3[m=(yloc*8+c)=32, x=128] over K'=4096, 64 chunks of 32 kpoints.
// Each wave: 2 x-fragments (x, x+64), 2 mf rows -> 16 MFMA/chunk (as v10).
// Straight-line loads first, B-side rotation, pack after MFMA, linear EyL.
// ---------------------------------------------------------------------------
__global__ __launch_bounds__(256) void adj_gemm(const uint* __restrict__ ExT,
                                                const uint* __restrict__ EyL,
                                                const float2* __restrict__ g,
                                                const float* __restrict__ csmap,
                                                float* __restrict__ out) {
    const int t = blockIdx.x, yt = blockIdx.y, ybase = yt * 4;
    const int tid = threadIdx.x, lane = tid & 63, ws = tid >> 6;
    const int quad = lane >> 4, l15 = lane & 15;

    __shared__ __align__(16) _Float16 Ts[2][32][72];    // 64 K'-halves + 8 pad

    f32x4 accr[2][2], acci[2][2];
#pragma unroll
    for (int mf = 0; mf < 2; ++mf)
#pragma unroll
        for (int nf = 0; nf < 2; ++nf) { accr[mf][nf] = (f32x4)0.0f; acci[mf][nf] = (f32x4)0.0f; }

    const float2* gBase = g + (size_t)t * NK * NC;
    const uint* eyBase = EyL + (size_t)t * NK * NXY;
    const uint* exR0 = ExT + (size_t)t * NXY * NK + (size_t)(ws * 16 + l15) * NK;
    const uint* exR1 = exR0 + (size_t)64 * NK;

    const int bm = tid >> 3, bu = tid & 3;          // row m (0..31), kp group
    const int bq = (tid >> 2) & 1;                  // which 16-kp half
    const int bk4 = bq * 16 + bu * 4;               // kpoint offset (0..28)
    const int by = ybase + (bm >> 3), bc = bm & 7;

    // build chunk 0
    {
        F8 w;
#pragma unroll
        for (int j = 0; j < 4; ++j) {
            int kp = bk4 + j;
            float2 gv = gBase[kp * NC + bc];
            float2 ey = unpack2h(eyBase[(size_t)kp * NXY + by]);
            w.u[j] = pack2h(ey.x * gv.x + ey.y * gv.y, ey.x * gv.y - ey.y * gv.x);
        }
        *(F8*)&Ts[0][bm][bk4 * 2] = w;
    }
    __syncthreads();

    for (int ch = 0; ch < 64; ++ch) {
        const int buf = ch & 1;
        const int chn = ch < 63 ? ch + 1 : 63;       // clamped: last iter redundant
        // --- issue ALL global loads for this iteration up front ---
        const int kb = chn * 32 + bk4;
        float2 gv0 = gBase[(kb + 0) * NC + bc];
        float2 gv1 = gBase[(kb + 1) * NC + bc];
        float2 gv2 = gBase[(kb + 2) * NC + bc];
        float2 gv3 = gBase[(kb + 3) * NC + bc];
        uint ev0 = eyBase[(size_t)(kb + 0) * NXY + by];
        uint ev1 = eyBase[(size_t)(kb + 1) * NXY + by];
        uint ev2 = eyBase[(size_t)(kb + 2) * NXY + by];
        uint ev3 = eyBase[(size_t)(kb + 3) * NXY + by];
        F8 Bf00 = *(const F8*)(exR0 + ch * 32 + quad * 4);
        F8 Bf01 = *(const F8*)(exR0 + ch * 32 + 16 + quad * 4);
        F8 Bf10 = *(const F8*)(exR1 + ch * 32 + quad * 4);
        F8 Bf11 = *(const F8*)(exR1 + ch * 32 + 16 + quad * 4);
        // B-side rotation for imag accumulator: Bi = (-bI, bR)
        F8 Bi00, Bi01, Bi10, Bi11;
#pragma unroll
        for (int d = 0; d < 4; ++d) {
            Bi00.u[d] = rot16(Bf00.u[d]) ^ 0x00008000u;
            Bi01.u[d] = rot16(Bf01.u[d]) ^ 0x00008000u;
            Bi10.u[d] = rot16(Bf10.u[d]) ^ 0x00008000u;
            Bi11.u[d] = rot16(Bf11.u[d]) ^ 0x00008000u;
        }
        // --- MFMA phase on Ts[buf] ---
#pragma unroll
        for (int mf = 0; mf < 2; ++mf) {
            F8 Ap0 = *(const F8*)&Ts[buf][mf * 16 + l15][quad * 8];
            accr[mf][0] = MFMA16(Ap0.h, Bf00.h, accr[mf][0]);
            acci[mf][0] = MFMA16(Ap0.h, Bi00.h, acci[mf][0]);
            accr[mf][1] = MFMA16(Ap0.h, Bf10.h, accr[mf][1]);
            acci[mf][1] = MFMA16(Ap0.h, Bi10.h, acci[mf][1]);
            F8 Ap1 = *(const F8*)&Ts[buf][mf * 16 + l15][32 + quad * 8];
            accr[mf][0] = MFMA16(Ap1.h, Bf01.h, accr[mf][0]);
            acci[mf][0] = MFMA16(Ap1.h, Bi01.h, acci[mf][0]);
            accr[mf][1] = MFMA16(Ap1.h, Bf11.h, accr[mf][1]);
            acci[mf][1] = MFMA16(Ap1.h, Bi11.h, acci[mf][1]);
        }
        // --- pack + write build for chunk ch+1 ---
        {
            F8 w; float2 e;
            e = unpack2h(ev0); w.u[0] = pack2h(e.x*gv0.x + e.y*gv0.y, e.x*gv0.y - e.y*gv0.x);
            e = unpack2h(ev1); w.u[1] = pack2h(e.x*gv1.x + e.y*gv1.y, e.x*gv1.y - e.y*gv1.x);
            e = unpack2h(ev2); w.u[2] = pack2h(e.x*gv2.x + e.y*gv2.y, e.x*gv2.y - e.y*gv2.x);
            e = unpack2h(ev3); w.u[3] = pack2h(e.x*gv3.x + e.y*gv3.y, e.x*gv3.y - e.y*gv3.x);
            *(F8*)&Ts[buf ^ 1][bm][bk4 * 2] = w;
        }
        __syncthreads();
    }

    // epilogue: coil-combine with conj(smap), write out[2][x][y][t]
#pragma unroll
    for (int mf = 0; mf < 2; ++mf)
#pragma unroll
        for (int nf = 0; nf < 2; ++nf) {
            const int y = ybase + 2 * mf + (quad >> 1);
            const int x = nf * 64 + ws * 16 + l15;
            float or_ = 0.f, oi_ = 0.f;
#pragma unroll
            for (int r = 0; r < 4; ++r) {
                int c = 4 * (quad & 1) + r;
                float sr = csmap[(size_t)c * 2 * NXY * NXY + x * NXY + y];
                float si = csmap[(size_t)c * 2 * NXY * NXY + NXY * NXY + x * NXY + y];
                float xr = accr[mf][nf][r], xi = acci[mf][nf][r];
                or_ += sr * xr + si * xi;
                oi_ += sr * xi - si * xr;
            }
            or_ += __shfl_xor(or_, 16);
            oi_ += __shfl_xor(oi_, 16);
            if ((lane & 16) == 0) {
                out[(size_t)(x * NXY + y) * NT + t] = or_;
                out[(size_t)NXY * NXY * NT + (size_t)(x * NXY + y) * NT + t] = oi_;
            }
        }
}

// ---------------------------------------------------------------------------
extern "C" void kernel_launch(void* const* d_in, const int* in_sizes, int n_in,
                              void* d_out, int out_size, void* d_ws, size_t ws_size,
                              hipStream_t stream) {
    const float* xin   = (const float*)d_in[0];  // (2,128,128,16)
    const float* ktraj = (const float*)d_in[1];  // (2,2048,16)
    const float* csmap = (const float*)d_in[2];  // (8,2,128,128)
    const float* dcomp = (const float*)d_in[3];  // (2048,16)
    float* out = (float*)d_out;                  // (2,128,128,16)

    // ws layout: ExC + ExT + EyL (16MB each) + srcB 8MB + g 2MB = 58MB
    const size_t TBL = (size_t)NT * NK * NXY;            // 4.19M dwords per table
    uint* ExC  = (uint*)d_ws;                            // [t][kt][xc][kp][xq]
    uint* ExT  = ExC + TBL;                              // [t][x][k]
    uint* EyL  = ExT + TBL;                              // [t][k][y]
    uint* srcB = EyL + TBL;                              // fragment-ordered
    float2* g  = (float2*)(srcB + (size_t)NT * NC * NXY * NXY);  // [t][k][c]

    prep_all<<<dim3(40960), 256, 0, stream>>>(ktraj, xin, csmap, ExC, ExT, EyL, srcB);
    fwd_gemm<<<dim3(NT, NC, 32), 256, 0, stream>>>(ExC, EyL, srcB, dcomp, g);
    adj_gemm<<<dim3(NT, 32), 256, 0, stream>>>(ExT, EyL, g, csmap, out);
}

// Round 13
// 225.702 us; speedup vs baseline: 1.3136x; 1.3136x over previous
//
#include <hip/hip_runtime.h>

// Frame-wise E^H D E exact NDFT via separable phasors as two complex GEMMs on
// fp16 matrix cores (fp32 accumulate).
// v14 = v12 (221.3us best) with:
//  - adj_gemm: v12/v10 VERBATIM (91us; v13's 2x256 split doubled B/build
//    traffic per CU -> 161us -> reverted).
//  - fwd_gemm: A no longer staged in LDS. srcB fragment interior permuted so a
//    wave's F8 A-read is a fully-coalesced 1KB load at lane*16B; each wave
//    reads its 8 mf fragments DIRECTLY from L2 (the 32 kt-blocks sharing one
//    64KB srcT slice sit on the same XCD: ID diff = 128 = 0 mod 8). Deletes
//    LDS round-trip and ALL per-chunk barriers; straight-line loads (v10
//    pattern), B-side rotation, in-wave epilogue kept.
//  - prep_all: identical except srcB store offset uses the new permutation.

#define NT 16
#define NK 2048
#define NXY 128
#define NC 8

typedef _Float16 f16x8 __attribute__((ext_vector_type(8)));
typedef float f32x4 __attribute__((ext_vector_type(4)));

union F8 { f16x8 h; uint u[4]; };

#define MFMA16(a, b, c) __builtin_amdgcn_mfma_f32_16x16x32_f16((a), (b), (c), 0, 0, 0)

__device__ __forceinline__ uint pack2h(float a, float b) {
    union { _Float16 h[2]; uint u; } p;
    p.h[0] = (_Float16)a; p.h[1] = (_Float16)b;
    return p.u;
}
__device__ __forceinline__ float2 unpack2h(uint v) {
    union { uint u; _Float16 h[2]; } p;
    p.u = v;
    return make_float2((float)p.h[0], (float)p.h[1]);
}
__device__ __forceinline__ uint rot16(uint v) { return (v >> 16) | (v << 16); }

// ---------------------------------------------------------------------------
// prep_all: fused preps, branch on block range (block-uniform divergence).
//  [0, 16384):      phasA -> tiled ExC [t][kt16][xc8][kp128][xq16] + linear
//                   EyL [t][k][y]
//  [16384, 32768):  phasB -> ExT [t][x][k]
//  [32768, 40960):  src   -> srcB [t][c][ch8][mf8][frag256] with frag offset
//                   (xl>>2)*64 + r*4 + (xl&3)  (wave F8 read = lane*16B)
// ---------------------------------------------------------------------------
__global__ __launch_bounds__(256) void prep_all(const float* __restrict__ ktraj,
                                                const float* __restrict__ xin,
                                                const float* __restrict__ csmap,
                                                uint* __restrict__ ExC,
                                                uint* __restrict__ ExT,
                                                uint* __restrict__ EyL,
                                                uint* __restrict__ srcB) {
    const int b = blockIdx.x;
    const int tid = threadIdx.x;
    if (b < 16384) {
        // ---- phasA ----
        const int t = b >> 10;
        const int k = (b & 1023) * 2 + (tid >> 7);
        const int x = tid & 127;
        const float kx = ktraj[(size_t)k * NT + t];
        const float ky = ktraj[(size_t)(NK + k) * NT + t];
        const float xm = (float)(x - 64);
        float s, c;
        __sincosf(-kx * xm, &s, &c);
        ExC[((size_t)(t * 16 + (k >> 7)) * 8 + (x >> 4)) * 2048 +
            (size_t)(k & 127) * 16 + (x & 15)] = pack2h(c, s);
        __sincosf(-ky * xm, &s, &c);
        EyL[((size_t)t * NK + k) * NXY + x] = pack2h(c, s);
    } else if (b < 32768) {
        // ---- phasB ----
        const int q = b - 16384;
        const int t = q >> 10, x = (q >> 3) & 127, kz = q & 7;
        const int k = kz * 256 + tid;
        const float kx = ktraj[(size_t)k * NT + t];
        float s, c;
        __sincosf(-kx * (float)(x - 64), &s, &c);
        ExT[((size_t)t * NXY + x) * NK + k] = pack2h(c, s);
    } else {
        // ---- src ----
        const int idx = (b - 32768) * 256 + tid;   // < 2^21
        const int t = idx & 15, r = (idx >> 4) & 15, xl = (idx >> 8) & 15,
                  mf = (idx >> 12) & 7, ch = (idx >> 15) & 7, c = idx >> 18;
        const int x = ch * 16 + xl, y = mf * 16 + r;
        const float ir = xin[(size_t)(x * NXY + y) * NT + t];
        const float ii = xin[(size_t)NXY * NXY * NT + (size_t)(x * NXY + y) * NT + t];
        const float sr = csmap[(size_t)c * 2 * NXY * NXY + x * NXY + y];
        const float si = csmap[(size_t)c * 2 * NXY * NXY + NXY * NXY + x * NXY + y];
        srcB[((size_t)(t * NC + c) << 14) + ch * 2048 + mf * 256 +
             (xl >> 2) * 64 + r * 4 + (xl & 3)] =
            pack2h(sr * ir - si * ii, sr * ii + si * ir);
    }
}

// ---------------------------------------------------------------------------
// fwd_gemm: block = (t, c, kt of 64 kpoints), 256 thr, 4 waves. BARRIER-FREE.
// Wave ws owns kp slice [kt*64+ws*16, +16), all 8 mf rows. Per chunk: 8 direct
// 1KB-coalesced A-loads from L2 (permuted srcB), 1 B-load, 16 MFMA. No LDS.
// Straight-line loads first (v10 pattern), B-side rotation, in-wave epilogue.
// ---------------------------------------------------------------------------
__global__ __launch_bounds__(256, 2) void fwd_gemm(const uint* __restrict__ ExC,
                                                   const uint* __restrict__ EyL,
                                                   const uint* __restrict__ srcB,
                                                   const float* __restrict__ dcomp,
                                                   float2* __restrict__ g) {
    const int t = blockIdx.x, c = blockIdx.y, kt = blockIdx.z;
    const int tid = threadIdx.x, lane = tid & 63, ws = tid >> 6;
    const int quad = lane >> 4, l15 = lane & 15;

    f32x4 accr[8], acci[8];
#pragma unroll
    for (int mf = 0; mf < 8; ++mf) { accr[mf] = (f32x4)0.0f; acci[mf] = (f32x4)0.0f; }

    const uint* srcT = srcB + ((size_t)(t * NC + c) << 14) + lane * 4;
    const uint* exB = ExC + (size_t)(t * 16 + (kt >> 1)) * 16384;
    const int kin0 = (kt & 1) * 64 + ws * 16;            // this wave's kp base (128-tile)

    F8 Bc = *(const F8*)(exB + (kin0 + l15) * 16 + quad * 4);

#pragma unroll 2
    for (int ch = 0; ch < 8; ++ch) {
        // --- straight-line: all loads for this chunk (+next B) first ---
        const int chn = ch < 7 ? ch + 1 : 7;
        F8 Bn = *(const F8*)(exB + chn * 2048 + (kin0 + l15) * 16 + quad * 4);
        F8 Ap[8];
#pragma unroll
        for (int mf = 0; mf < 8; ++mf)
            Ap[mf] = *(const F8*)(srcT + ch * 2048 + mf * 256);
        // B-side rotation: Br = (bR,-bI) for real part, Bi = (bI,bR) for imag
        F8 Br, Bi;
#pragma unroll
        for (int d = 0; d < 4; ++d) {
            Br.u[d] = Bc.u[d] ^ 0x80000000u;
            Bi.u[d] = rot16(Bc.u[d]);
        }
#pragma unroll
        for (int mf = 0; mf < 8; ++mf) {
            accr[mf] = MFMA16(Ap[mf].h, Br.h, accr[mf]);
            acci[mf] = MFMA16(Ap[mf].h, Bi.h, acci[mf]);
        }
        Bc = Bn;
    }

    // epilogue: in-wave y-reduction with EyL (all 8 mf), quad-reduce, store g
    const int kpoint = kt * 64 + ws * 16 + l15;
    const uint* eyRow = EyL + ((size_t)t * NK + kpoint) * NXY;
    float kdr = 0.f, kdi = 0.f;
#pragma unroll
    for (int mf = 0; mf < 8; ++mf) {
        F8 e4 = *(const F8*)(eyRow + mf * 16 + quad * 4);
#pragma unroll
        for (int rr = 0; rr < 4; ++rr) {
            float2 ey = unpack2h(e4.u[rr]);
            float cr = accr[mf][rr], ci = acci[mf][rr];
            kdr += ey.x * cr - ey.y * ci;
            kdi += ey.x * ci + ey.y * cr;
        }
    }
    kdr += __shfl_xor(kdr, 16); kdr += __shfl_xor(kdr, 32);
    kdi += __shfl_xor(kdi, 16); kdi += __shfl_xor(kdi, 32);
    if (lane < 16) {
        float w = dcomp[(size_t)kpoint * NT + t] * (1.0f / 16384.0f);
        g[((size_t)t * NK + kpoint) * NC + c] = make_float2(kdr * w, kdi * w);
    }
}

// ---------------------------------------------------------------------------
// adj_gemm: block = (t, ytile of 8 y), 512 thr (8 waves).  (v10/v12 VERBATIM:
// straight-line loads first, B-side rotation, pack after MFMA, linear EyL.)
// ---------------------------------------------------------------------------
__global__ __launch_bounds__(512) void adj_gemm(const uint* __restrict__ ExT,
                                                const uint* __restrict__ EyL,
                                                const float2* __restrict__ g,
                                                const float* __restrict__ csmap,
                                                float* __restrict__ out) {
    const int t = blockIdx.x, yt = blockIdx.y, ybase = yt * 8;
    const int tid = threadIdx.x, lane = tid & 63, ws = tid >> 6;
    const int quad = lane >> 4, l15 = lane & 15;
    const int x = ws * 16 + l15;

    __shared__ __align__(16) _Float16 Ts[2][64][72];    // 64 K'-halves + 8 pad

    f32x4 accr[4], acci[4];
#pragma unroll
    for (int mf = 0; mf < 4; ++mf) { accr[mf] = (f32x4)0.0f; acci[mf] = (f32x4)0.0f; }

    const float2* gBase = g + (size_t)t * NK * NC;
    const uint* eyBase = EyL + (size_t)t * NK * NXY;
    const uint* exRow = ExT + (size_t)t * NXY * NK + (size_t)x * NK;

    const int bm = tid & 63;                 // build: row m
    const int bk4 = (tid >> 6) * 4;          // build: kpoint offset (0..28)
    const int by = ybase + (bm >> 3), bc = bm & 7;

    // build chunk 0
    {
        F8 w;
#pragma unroll
        for (int j = 0; j < 4; ++j) {
            int kp = bk4 + j;
            float2 gv = gBase[kp * NC + bc];
            float2 ey = unpack2h(eyBase[(size_t)kp * NXY + by]);
            w.u[j] = pack2h(ey.x * gv.x + ey.y * gv.y, ey.x * gv.y - ey.y * gv.x);
        }
        *(F8*)&Ts[0][bm][bk4 * 2] = w;
    }
    __syncthreads();

    for (int ch = 0; ch < 64; ++ch) {
        const int buf = ch & 1;
        const int chn = ch < 63 ? ch + 1 : 63;       // clamped: last iter redundant
        // --- issue ALL global loads for this iteration up front ---
        const int kb = chn * 32 + bk4;
        float2 gv0 = gBase[(kb + 0) * NC + bc];
        float2 gv1 = gBase[(kb + 1) * NC + bc];
        float2 gv2 = gBase[(kb + 2) * NC + bc];
        float2 gv3 = gBase[(kb + 3) * NC + bc];
        uint ev0 = eyBase[(size_t)(kb + 0) * NXY + by];
        uint ev1 = eyBase[(size_t)(kb + 1) * NXY + by];
        uint ev2 = eyBase[(size_t)(kb + 2) * NXY + by];
        uint ev3 = eyBase[(size_t)(kb + 3) * NXY + by];
        F8 Bf0 = *(const F8*)(exRow + ch * 32 + quad * 4);
        F8 Bf1 = *(const F8*)(exRow + ch * 32 + 16 + quad * 4);
        // B-side rotation for imag accumulator: Bi = (-bI, bR)
        F8 Bi0, Bi1;
#pragma unroll
        for (int d = 0; d < 4; ++d) {
            Bi0.u[d] = rot16(Bf0.u[d]) ^ 0x00008000u;
            Bi1.u[d] = rot16(Bf1.u[d]) ^ 0x00008000u;
        }
        // --- MFMA phase on Ts[buf] ---
#pragma unroll
        for (int mf = 0; mf < 4; ++mf) {
            F8 Ap0 = *(const F8*)&Ts[buf][mf * 16 + l15][quad * 8];
            accr[mf] = MFMA16(Ap0.h, Bf0.h, accr[mf]);
            acci[mf] = MFMA16(Ap0.h, Bi0.h, acci[mf]);
            F8 Ap1 = *(const F8*)&Ts[buf][mf * 16 + l15][32 + quad * 8];
            accr[mf] = MFMA16(Ap1.h, Bf1.h, accr[mf]);
            acci[mf] = MFMA16(Ap1.h, Bi1.h, acci[mf]);
        }
        // --- pack + write build for chunk ch+1 ---
        {
            F8 w; float2 e;
            e = unpack2h(ev0); w.u[0] = pack2h(e.x*gv0.x + e.y*gv0.y, e.x*gv0.y - e.y*gv0.x);
            e = unpack2h(ev1); w.u[1] = pack2h(e.x*gv1.x + e.y*gv1.y, e.x*gv1.y - e.y*gv1.x);
            e = unpack2h(ev2); w.u[2] = pack2h(e.x*gv2.x + e.y*gv2.y, e.x*gv2.y - e.y*gv2.x);
            e = unpack2h(ev3); w.u[3] = pack2h(e.x*gv3.x + e.y*gv3.y, e.x*gv3.y - e.y*gv3.x);
            *(F8*)&Ts[buf ^ 1][bm][bk4 * 2] = w;
        }
        __syncthreads();
    }

    // epilogue: coil-combine with conj(smap), write out[2][x][y][t]
#pragma unroll
    for (int mf = 0; mf < 4; ++mf) {
        const int y = ybase + 2 * mf + (quad >> 1);
        float or_ = 0.f, oi_ = 0.f;
#pragma unroll
        for (int r = 0; r < 4; ++r) {
            int c = 4 * (quad & 1) + r;
            float sr = csmap[(size_t)c * 2 * NXY * NXY + x * NXY + y];
            float si = csmap[(size_t)c * 2 * NXY * NXY + NXY * NXY + x * NXY + y];
            float xr = accr[mf][r], xi = acci[mf][r];
            or_ += sr * xr + si * xi;
            oi_ += sr * xi - si * xr;
        }
        or_ += __shfl_xor(or_, 16);
        oi_ += __shfl_xor(oi_, 16);
        if ((lane & 16) == 0) {
            out[(size_t)(x * NXY + y) * NT + t] = or_;
            out[(size_t)NXY * NXY * NT + (size_t)(x * NXY + y) * NT + t] = oi_;
        }
    }
}

// ---------------------------------------------------------------------------
extern "C" void kernel_launch(void* const* d_in, const int* in_sizes, int n_in,
                              void* d_out, int out_size, void* d_ws, size_t ws_size,
                              hipStream_t stream) {
    const float* xin   = (const float*)d_in[0];  // (2,128,128,16)
    const float* ktraj = (const float*)d_in[1];  // (2,2048,16)
    const float* csmap = (const float*)d_in[2];  // (8,2,128,128)
    const float* dcomp = (const float*)d_in[3];  // (2048,16)
    float* out = (float*)d_out;                  // (2,128,128,16)

    // ws layout: ExC + ExT + EyL (16MB each) + srcB 8MB + g 2MB = 58MB
    const size_t TBL = (size_t)NT * NK * NXY;            // 4.19M dwords per table
    uint* ExC  = (uint*)d_ws;                            // [t][kt][xc][kp][xq]
    uint* ExT  = ExC + TBL;                              // [t][x][k]
    uint* EyL  = ExT + TBL;                              // [t][k][y]
    uint* srcB = EyL + TBL;                              // fragment-ordered (permuted)
    float2* g  = (float2*)(srcB + (size_t)NT * NC * NXY * NXY);  // [t][k][c]

    prep_all<<<dim3(40960), 256, 0, stream>>>(ktraj, xin, csmap, ExC, ExT, EyL, srcB);
    fwd_gemm<<<dim3(NT, NC, 32), 256, 0, stream>>>(ExC, EyL, srcB, dcomp, g);
    adj_gemm<<<dim3(NT, NXY / 8), 512, 0, stream>>>(ExT, EyL, g, csmap, out);
}

// Round 14
// 217.867 us; speedup vs baseline: 1.3609x; 1.0360x over previous
//
#include <hip/hip_runtime.h>

// Frame-wise E^H D E exact NDFT via separable phasors as two complex GEMMs on
// fp16 matrix cores (fp32 accumulate).
// v15 = v12 (221.3us best) with adj K-SPLIT kz=2 + partial buffers:
//  - adj_gemm: grid (NT,16,2); block kz processes kpoints [kz*1024, +1024)
//    (32 chunks). Siblings read DISJOINT halves of ExT/g/EyL -> zero traffic
//    duplication (v13's failure), and write private f32 partial buffers ->
//    no atomics (v4's failure). 2 blocks/CU: one block's latency/barrier
//    phases overlap the other's MFMA. Loop body v10/v12 VERBATIM.
//  - combine: out = part0 + part1 (2MB elementwise, ~2us).
//  - fwd_gemm / prep_all: v12 verbatim (v14's direct-L2 fwd was +3us; reverted).

#define NT 16
#define NK 2048
#define NXY 128
#define NC 8

typedef _Float16 f16x8 __attribute__((ext_vector_type(8)));
typedef float f32x4 __attribute__((ext_vector_type(4)));

union F8 { f16x8 h; uint u[4]; };

#define MFMA16(a, b, c) __builtin_amdgcn_mfma_f32_16x16x32_f16((a), (b), (c), 0, 0, 0)

__device__ __forceinline__ uint pack2h(float a, float b) {
    union { _Float16 h[2]; uint u; } p;
    p.h[0] = (_Float16)a; p.h[1] = (_Float16)b;
    return p.u;
}
__device__ __forceinline__ float2 unpack2h(uint v) {
    union { uint u; _Float16 h[2]; } p;
    p.u = v;
    return make_float2((float)p.h[0], (float)p.h[1]);
}
__device__ __forceinline__ uint rot16(uint v) { return (v >> 16) | (v << 16); }

// ---------------------------------------------------------------------------
// prep_all: fused preps, branch on block range (block-uniform divergence).
//  [0, 16384):      phasA -> tiled ExC [t][kt16][xc8][kp128][xq16] + linear
//                   EyL [t][k][y]
//  [16384, 32768):  phasB -> ExT [t][x][k]
//  [32768, 40960):  src   -> srcB fragment order [t][c][ch8][mf8][r16][xl16]
// ---------------------------------------------------------------------------
__global__ __launch_bounds__(256) void prep_all(const float* __restrict__ ktraj,
                                                const float* __restrict__ xin,
                                                const float* __restrict__ csmap,
                                                uint* __restrict__ ExC,
                                                uint* __restrict__ ExT,
                                                uint* __restrict__ EyL,
                                                uint* __restrict__ srcB) {
    const int b = blockIdx.x;
    const int tid = threadIdx.x;
    if (b < 16384) {
        // ---- phasA ----
        const int t = b >> 10;
        const int k = (b & 1023) * 2 + (tid >> 7);
        const int x = tid & 127;
        const float kx = ktraj[(size_t)k * NT + t];
        const float ky = ktraj[(size_t)(NK + k) * NT + t];
        const float xm = (float)(x - 64);
        float s, c;
        __sincosf(-kx * xm, &s, &c);
        ExC[((size_t)(t * 16 + (k >> 7)) * 8 + (x >> 4)) * 2048 +
            (size_t)(k & 127) * 16 + (x & 15)] = pack2h(c, s);
        __sincosf(-ky * xm, &s, &c);
        EyL[((size_t)t * NK + k) * NXY + x] = pack2h(c, s);
    } else if (b < 32768) {
        // ---- phasB ----
        const int q = b - 16384;
        const int t = q >> 10, x = (q >> 3) & 127, kz = q & 7;
        const int k = kz * 256 + tid;
        const float kx = ktraj[(size_t)k * NT + t];
        float s, c;
        __sincosf(-kx * (float)(x - 64), &s, &c);
        ExT[((size_t)t * NXY + x) * NK + k] = pack2h(c, s);
    } else {
        // ---- src ----
        const int idx = (b - 32768) * 256 + tid;   // < 2^21
        const int t = idx & 15, r = (idx >> 4) & 15, xl = (idx >> 8) & 15,
                  mf = (idx >> 12) & 7, ch = (idx >> 15) & 7, c = idx >> 18;
        const int x = ch * 16 + xl, y = mf * 16 + r;
        const float ir = xin[(size_t)(x * NXY + y) * NT + t];
        const float ii = xin[(size_t)NXY * NXY * NT + (size_t)(x * NXY + y) * NT + t];
        const float sr = csmap[(size_t)c * 2 * NXY * NXY + x * NXY + y];
        const float si = csmap[(size_t)c * 2 * NXY * NXY + NXY * NXY + x * NXY + y];
        srcB[((size_t)(t * NC + c) << 14) + ch * 2048 + mf * 256 + r * 16 + xl] =
            pack2h(sr * ir - si * ii, sr * ii + si * ir);
    }
}

// ---------------------------------------------------------------------------
// fwd_gemm: block = (t, c, kt of 64 kpoints), 256 thr, 4 waves.  (v12 verbatim)
// Wave ws owns kp slice [kt*64 + ws*16, +16) and ALL 8 mf rows. 1 B-load per
// chunk per wave, in-wave epilogue, B-side complex rotation.
// ---------------------------------------------------------------------------
__global__ __launch_bounds__(256, 2) void fwd_gemm(const uint* __restrict__ ExC,
                                                   const uint* __restrict__ EyL,
                                                   const uint* __restrict__ srcB,
                                                   const float* __restrict__ dcomp,
                                                   float2* __restrict__ g) {
    const int t = blockIdx.x, c = blockIdx.y, kt = blockIdx.z;
    const int tid = threadIdx.x, lane = tid & 63, ws = tid >> 6;
    const int quad = lane >> 4, l15 = lane & 15;

    __shared__ __align__(16) _Float16 As[2][4096];

    f32x4 accr[8], acci[8];
#pragma unroll
    for (int mf = 0; mf < 8; ++mf) { accr[mf] = (f32x4)0.0f; acci[mf] = (f32x4)0.0f; }

    const uint* srcT = srcB + ((size_t)(t * NC + c) << 14);
    const uint* exB = ExC + (size_t)(t * 16 + (kt >> 1)) * 16384;
    const int kin0 = (kt & 1) * 64 + ws * 16;            // this wave's kp base (128-tile)

    // prologue: stage + B load for chunk 0
    F8 vA0 = *(const F8*)(srcT + tid * 8);
    F8 vA1 = *(const F8*)(srcT + tid * 8 + 4);
    F8 Bc = *(const F8*)(exB + (kin0 + l15) * 16 + quad * 4);

#pragma unroll 2
    for (int ch = 0; ch < 8; ++ch) {
        const int buf = ch & 1;
        *(F8*)&As[buf][tid * 16] = vA0;
        *(F8*)&As[buf][tid * 16 + 8] = vA1;
        __syncthreads();
        const int chn = ch < 7 ? ch + 1 : 7;
        vA0 = *(const F8*)(srcT + chn * 2048 + tid * 8);
        vA1 = *(const F8*)(srcT + chn * 2048 + tid * 8 + 4);
        F8 Bn = *(const F8*)(exB + chn * 2048 + (kin0 + l15) * 16 + quad * 4);
        __builtin_amdgcn_sched_barrier(0);
        // B-side rotation: Br = (bR,-bI) for real part, Bi = (bI,bR) for imag
        F8 Br, Bi;
#pragma unroll
        for (int d = 0; d < 4; ++d) {
            Br.u[d] = Bc.u[d] ^ 0x80000000u;
            Bi.u[d] = rot16(Bc.u[d]);
        }
#pragma unroll
        for (int mf = 0; mf < 8; ++mf) {
            F8 Ap = *(const F8*)&As[buf][mf * 512 + l15 * 32 + quad * 8];
            accr[mf] = MFMA16(Ap.h, Br.h, accr[mf]);
            acci[mf] = MFMA16(Ap.h, Bi.h, acci[mf]);
        }
        Bc = Bn;
    }

    // epilogue: in-wave y-reduction with EyL (all 8 mf), quad-reduce, store g
    const int kpoint = kt * 64 + ws * 16 + l15;
    const uint* eyRow = EyL + ((size_t)t * NK + kpoint) * NXY;
    float kdr = 0.f, kdi = 0.f;
#pragma unroll
    for (int mf = 0; mf < 8; ++mf) {
        F8 e4 = *(const F8*)(eyRow + mf * 16 + quad * 4);
#pragma unroll
        for (int rr = 0; rr < 4; ++rr) {
            float2 ey = unpack2h(e4.u[rr]);
            float cr = accr[mf][rr], ci = acci[mf][rr];
            kdr += ey.x * cr - ey.y * ci;
            kdi += ey.x * ci + ey.y * cr;
        }
    }
    kdr += __shfl_xor(kdr, 16); kdr += __shfl_xor(kdr, 32);
    kdi += __shfl_xor(kdi, 16); kdi += __shfl_xor(kdi, 32);
    if (lane < 16) {
        float w = dcomp[(size_t)kpoint * NT + t] * (1.0f / 16384.0f);
        g[((size_t)t * NK + kpoint) * NC + c] = make_float2(kdr * w, kdi * w);
    }
}

// ---------------------------------------------------------------------------
// adj_gemm: block = (t, ytile of 8 y, kz of 2 k-halves), 512 thr (8 waves).
// Each block: K' = 2048 halves (1024 kpoints), 32 chunks of 32 kpoints.
// Siblings read disjoint ExT/g/EyL halves (no traffic duplication); write
// private f32 partial buffers (no atomics). Loop body v10/v12 VERBATIM.
// ---------------------------------------------------------------------------
__global__ __launch_bounds__(512) void adj_gemm(const uint* __restrict__ ExT,
                                                const uint* __restrict__ EyL,
                                                const float2* __restrict__ g,
                                                const float* __restrict__ csmap,
                                                float* __restrict__ part) {
    const int t = blockIdx.x, yt = blockIdx.y, kz = blockIdx.z, ybase = yt * 8;
    const int tid = threadIdx.x, lane = tid & 63, ws = tid >> 6;
    const int quad = lane >> 4, l15 = lane & 15;
    const int x = ws * 16 + l15;
    const int kbase = kz * 1024;

    __shared__ __align__(16) _Float16 Ts[2][64][72];    // 64 K'-halves + 8 pad

    f32x4 accr[4], acci[4];
#pragma unroll
    for (int mf = 0; mf < 4; ++mf) { accr[mf] = (f32x4)0.0f; acci[mf] = (f32x4)0.0f; }

    const float2* gBase = g + (size_t)t * NK * NC;
    const uint* eyBase = EyL + (size_t)t * NK * NXY;
    const uint* exRow = ExT + (size_t)t * NXY * NK + (size_t)x * NK + kbase;

    const int bm = tid & 63;                 // build: row m
    const int bk4 = (tid >> 6) * 4;          // build: kpoint offset (0..28)
    const int by = ybase + (bm >> 3), bc = bm & 7;

    // build chunk 0
    {
        F8 w;
#pragma unroll
        for (int j = 0; j < 4; ++j) {
            int kp = kbase + bk4 + j;
            float2 gv = gBase[kp * NC + bc];
            float2 ey = unpack2h(eyBase[(size_t)kp * NXY + by]);
            w.u[j] = pack2h(ey.x * gv.x + ey.y * gv.y, ey.x * gv.y - ey.y * gv.x);
        }
        *(F8*)&Ts[0][bm][bk4 * 2] = w;
    }
    __syncthreads();

    for (int ch = 0; ch < 32; ++ch) {
        const int buf = ch & 1;
        const int chn = ch < 31 ? ch + 1 : 31;       // clamped: last iter redundant
        // --- issue ALL global loads for this iteration up front ---
        const int kb = kbase + chn * 32 + bk4;
        float2 gv0 = gBase[(kb + 0) * NC + bc];
        float2 gv1 = gBase[(kb + 1) * NC + bc];
        float2 gv2 = gBase[(kb + 2) * NC + bc];
        float2 gv3 = gBase[(kb + 3) * NC + bc];
        uint ev0 = eyBase[(size_t)(kb + 0) * NXY + by];
        uint ev1 = eyBase[(size_t)(kb + 1) * NXY + by];
        uint ev2 = eyBase[(size_t)(kb + 2) * NXY + by];
        uint ev3 = eyBase[(size_t)(kb + 3) * NXY + by];
        F8 Bf0 = *(const F8*)(exRow + ch * 32 + quad * 4);
        F8 Bf1 = *(const F8*)(exRow + ch * 32 + 16 + quad * 4);
        // B-side rotation for imag accumulator: Bi = (-bI, bR)
        F8 Bi0, Bi1;
#pragma unroll
        for (int d = 0; d < 4; ++d) {
            Bi0.u[d] = rot16(Bf0.u[d]) ^ 0x00008000u;
            Bi1.u[d] = rot16(Bf1.u[d]) ^ 0x00008000u;
        }
        // --- MFMA phase on Ts[buf] ---
#pragma unroll
        for (int mf = 0; mf < 4; ++mf) {
            F8 Ap0 = *(const F8*)&Ts[buf][mf * 16 + l15][quad * 8];
            accr[mf] = MFMA16(Ap0.h, Bf0.h, accr[mf]);
            acci[mf] = MFMA16(Ap0.h, Bi0.h, acci[mf]);
            F8 Ap1 = *(const F8*)&Ts[buf][mf * 16 + l15][32 + quad * 8];
            accr[mf] = MFMA16(Ap1.h, Bf1.h, accr[mf]);
            acci[mf] = MFMA16(Ap1.h, Bi1.h, acci[mf]);
        }
        // --- pack + write build for chunk ch+1 ---
        {
            F8 w; float2 e;
            e = unpack2h(ev0); w.u[0] = pack2h(e.x*gv0.x + e.y*gv0.y, e.x*gv0.y - e.y*gv0.x);
            e = unpack2h(ev1); w.u[1] = pack2h(e.x*gv1.x + e.y*gv1.y, e.x*gv1.y - e.y*gv1.x);
            e = unpack2h(ev2); w.u[2] = pack2h(e.x*gv2.x + e.y*gv2.y, e.x*gv2.y - e.y*gv2.x);
            e = unpack2h(ev3); w.u[3] = pack2h(e.x*gv3.x + e.y*gv3.y, e.x*gv3.y - e.y*gv3.x);
            *(F8*)&Ts[buf ^ 1][bm][bk4 * 2] = w;
        }
        __syncthreads();
    }

    // epilogue: coil-combine with conj(smap), write partial [kz][2][x][y][t]
    float* po = part + (size_t)kz * 2 * NXY * NXY * NT;
#pragma unroll
    for (int mf = 0; mf < 4; ++mf) {
        const int y = ybase + 2 * mf + (quad >> 1);
        float or_ = 0.f, oi_ = 0.f;
#pragma unroll
        for (int r = 0; r < 4; ++r) {
            int c = 4 * (quad & 1) + r;
            float sr = csmap[(size_t)c * 2 * NXY * NXY + x * NXY + y];
            float si = csmap[(size_t)c * 2 * NXY * NXY + NXY * NXY + x * NXY + y];
            float xr = accr[mf][r], xi = acci[mf][r];
            or_ += sr * xr + si * xi;
            oi_ += sr * xi - si * xr;
        }
        or_ += __shfl_xor(or_, 16);
        oi_ += __shfl_xor(oi_, 16);
        if ((lane & 16) == 0) {
            po[(size_t)(x * NXY + y) * NT + t] = or_;
            po[(size_t)NXY * NXY * NT + (size_t)(x * NXY + y) * NT + t] = oi_;
        }
    }
}

// ---------------------------------------------------------------------------
// combine: out = part0 + part1 (elementwise over 2*128*128*16 floats)
// ---------------------------------------------------------------------------
__global__ __launch_bounds__(256) void combine(const float* __restrict__ part,
                                               float* __restrict__ out) {
    const int idx = blockIdx.x * 256 + threadIdx.x;      // < 524288
    out[idx] = part[idx] + part[idx + 2 * NXY * NXY * NT];
}

// ---------------------------------------------------------------------------
extern "C" void kernel_launch(void* const* d_in, const int* in_sizes, int n_in,
                              void* d_out, int out_size, void* d_ws, size_t ws_size,
                              hipStream_t stream) {
    const float* xin   = (const float*)d_in[0];  // (2,128,128,16)
    const float* ktraj = (const float*)d_in[1];  // (2,2048,16)
    const float* csmap = (const float*)d_in[2];  // (8,2,128,128)
    const float* dcomp = (const float*)d_in[3];  // (2048,16)
    float* out = (float*)d_out;                  // (2,128,128,16)

    // ws layout: ExC + ExT + EyL (16MB each) + srcB 8MB + g 2MB + part 4MB = 62MB
    const size_t TBL = (size_t)NT * NK * NXY;            // 4.19M dwords per table
    uint* ExC  = (uint*)d_ws;                            // [t][kt][xc][kp][xq]
    uint* ExT  = ExC + TBL;                              // [t][x][k]
    uint* EyL  = ExT + TBL;                              // [t][k][y]
    uint* srcB = EyL + TBL;                              // fragment-ordered
    float2* g  = (float2*)(srcB + (size_t)NT * NC * NXY * NXY);  // [t][k][c]
    float* part = (float*)(g + (size_t)NT * NK * NC);    // [kz][2][x][y][t]

    prep_all<<<dim3(40960), 256, 0, stream>>>(ktraj, xin, csmap, ExC, ExT, EyL, srcB);
    fwd_gemm<<<dim3(NT, NC, 32), 256, 0, stream>>>(ExC, EyL, srcB, dcomp, g);
    adj_gemm<<<dim3(NT, NXY / 8, 2), 512, 0, stream>>>(ExT, EyL, g, csmap, part);
    combine<<<dim3(2048), 256, 0, stream>>>(part, out);
}